// Round 7
// baseline (39.786 us; speedup 1.0000x reference)
//
#include <hip/hip_runtime.h>
#include <hip/hip_bf16.h>
#include <math.h>

typedef __bf16 bf16_t;
typedef __attribute__((ext_vector_type(8))) __bf16 bf16x8;
typedef __attribute__((ext_vector_type(4))) float f32x4;

#define NN 2048
#define CC 256
#define BB 16

// Sub-transforms (out[k], k=0..2047):
//  EE: out[4i]   = sum_{p=0}^{256} ee[p] cos(2pi*p*i/512),       i=0..255 (+mirror; k=1024 via GEMV)
//  EO: out[4i+2] = sum_{m=0}^{255} eo[m] cos(2pi*m*(2i+1)/1024), i=0..255 (+mirror)
//  O : out[2j+1] = sum_{m=0}^{511} o[m]  cos(2pi*m*(2j+1)/2048), j=0..511 (+mirror)
//  O K-axis PERMUTED: u<256 -> m=u ; u==256 -> m=256 ; u>256 -> m=768-u
#define KEE 320            // 257 padded to 5*64
#define KEO 256
#define KO  512

#define ANG2 (6.283185307179586f / 2048.0f)
#define ANG1 (6.283185307179586f / 1024.0f)
#define ANG0 (6.283185307179586f / 512.0f)

// Y LDS element offsets (bf16 elems): Yee[16][320], Yeo[16][256], Yo[16][512]
#define YEE_OFF 0
#define YEO_OFF (16 * KEE)              // 5120
#define YO_OFF  (YEO_OFF + 16 * KEO)    // 9216
#define Y_ELEMS (YO_OFF + 16 * KO)      // 17408

__device__ __forceinline__ void gload_lds16(const void* g, void* l) {
    __builtin_amdgcn_global_load_lds(
        (const __attribute__((address_space(1))) void*)g,
        (__attribute__((address_space(3))) void*)l, 16, 0, 0);
}

union V8 { bf16_t h[8]; uint4 v; };

// chunk-XOR swizzle within aligned groups of 8 16B-chunks (rows are 128B-multiples)
__device__ __forceinline__ int swz8(int p, int colk) {
    const int c = p >> 3;
    return (((c & ~7) | ((c & 7) ^ colk)) << 3) + (p & 7);
}

// ---------------- kernel 1: build A matrices (R6-proven, verbatim math) ----
#define NBLK_AEE 40
#define NBLK_AEO 32
#define NBLK_AO  128
#define NBLK_A   (NBLK_AEE + NBLK_AEO + NBLK_AO)

__global__ __launch_bounds__(256) void build_A_kernel(
    bf16_t* __restrict__ Aee, bf16_t* __restrict__ Aeo, bf16_t* __restrict__ Ao)
{
    const int blk = blockIdx.x;
    const int t = threadIdx.x;

    if (blk < NBLK_AEE) {              // Aee[i][p] = cos(2pi*p*i/512), zero p>256
        const int u = blk * 256 + t;
        const int i = u / 40;
        const int p0 = (u - i * 40) * 8;
        const unsigned step = (unsigned)i & 511u;
        unsigned ph = ((unsigned)i * (unsigned)p0) & 511u;
        V8 vals;
#pragma unroll
        for (int q = 0; q < 8; ++q) {
            vals.h[q] = (p0 + q <= 256) ? (bf16_t)cosf((float)ph * ANG0) : (bf16_t)0.0f;
            ph = (ph + step) & 511u;
        }
        *reinterpret_cast<uint4*>(Aee + (size_t)i * KEE + p0) = vals.v;
        return;
    }
    if (blk < NBLK_AEE + NBLK_AEO) {   // Aeo[i][m] = cos(2pi*m*(2i+1)/1024)
        const int u = (blk - NBLK_AEE) * 256 + t;
        const int i = u >> 5;
        const int m0 = (u & 31) * 8;
        const unsigned tw = 2u * (unsigned)i + 1u;
        unsigned ph = ((unsigned)m0 * tw) & 1023u;
        V8 vals;
#pragma unroll
        for (int q = 0; q < 8; ++q) {
            vals.h[q] = (bf16_t)cosf((float)ph * ANG1);
            ph = (ph + tw) & 1023u;
        }
        *reinterpret_cast<uint4*>(Aeo + (size_t)i * KEO + m0) = vals.v;
        return;
    }
    {                                  // Ao[j][u] = cos(2pi*m(u)*(2j+1)/2048)
        const int u = (blk - NBLK_AEE - NBLK_AEO) * 256 + t;
        const int j = u >> 6;
        const int u0 = (u & 63) * 8;
        const unsigned tw = 2u * (unsigned)j + 1u;
        V8 vals;
#pragma unroll
        for (int q = 0; q < 8; ++q) {
            const int uu = u0 + q;
            const int m = (uu <= 256) ? uu : (768 - uu);
            const unsigned ph = ((unsigned)m * tw) & 2047u;
            vals.h[q] = (bf16_t)cosf((float)ph * ANG2);
        }
        *reinterpret_cast<uint4*>(Ao + (size_t)j * KO + u0) = vals.v;
    }
}

// ---------------- GEMM section: M=256 rows x N=16 cols, A from global ws ----
// dbuf LDS A staging (linear dest + pre-swizzled source, R6-proven), B from Y LDS.
__device__ __forceinline__ void gemm_section(
    const bf16_t* __restrict__ Abase, const int K,
    const bf16_t* __restrict__ Ylds, const int ybase,
    bf16_t* __restrict__ AsBuf,
    float* __restrict__ outp, const int sec, const int t)
{
    const int steps = K >> 6;
    const int lane = t & 63;
    const int w = t >> 6;              // wave 0..7 -> rows w*32..w*32+31
    const int srow = t >> 3;           // staging row 0..63
    const int schunk = t & 7;
    const int lrow = lane & 15;
    const int rgrp = lane >> 4;        // 0..3
    const int rx = lane & 7;
    const int swsrc = (schunk ^ (srow & 7)) * 8;
    const int dlin = srow * 64 + schunk * 8;

    f32x4 acc0 = {0.f, 0.f, 0.f, 0.f}, acc1 = {0.f, 0.f, 0.f, 0.f};

    int cur = 0;
#pragma unroll
    for (int it = 0; it < 4; ++it)
        gload_lds16(Abase + (size_t)(srow + it * 64) * K + swsrc,
                    AsBuf + dlin + it * 4096);
    __syncthreads();
    for (int kt = 0; kt < steps; ++kt) {
        if (kt + 1 < steps) {
            const int k0 = (kt + 1) << 6;
            bf16_t* dst = AsBuf + (cur ^ 1) * 16384;
#pragma unroll
            for (int it = 0; it < 4; ++it)
                gload_lds16(Abase + (size_t)(srow + it * 64) * K + k0 + swsrc,
                            dst + dlin + it * 4096);
        }
        const bf16_t* as = AsBuf + cur * 16384;
#pragma unroll
        for (int kk = 0; kk < 64; kk += 32) {
            const int gA = (kk >> 3) + rgrp;
            const int rcA = (gA ^ rx) * 8;
            const int gB = (kt << 3) + gA;
            const int rcB = ((gB & ~7) | ((gB & 7) ^ rx)) * 8;
            const bf16x8 bfr = *(const bf16x8*)&Ylds[ybase + lrow * K + rcB];
            const bf16x8 af0 = *(const bf16x8*)&as[(w * 32 + lrow) * 64 + rcA];
            const bf16x8 af1 = *(const bf16x8*)&as[(w * 32 + 16 + lrow) * 64 + rcA];
            acc0 = __builtin_amdgcn_mfma_f32_16x16x32_bf16(af0, bfr, acc0, 0, 0, 0);
            acc1 = __builtin_amdgcn_mfma_f32_16x16x32_bf16(af1, bfr, acc1, 0, 0, 0);
        }
        __syncthreads();
        cur ^= 1;
    }
    // epilogue: D col = lane&15 (= output col), row = rgrp*4 + r
#pragma unroll
    for (int m = 0; m < 2; ++m) {
        const f32x4 a = m ? acc1 : acc0;
#pragma unroll
        for (int r = 0; r < 4; ++r) {
            const int i = w * 32 + m * 16 + rgrp * 4 + r;   // 0..255
            const float v = a[r];
            if (sec == 0) {
                outp[(size_t)(4 * i) * CC + lrow] = v;
                if (i >= 1) outp[(size_t)(2048 - 4 * i) * CC + lrow] = v;
            } else if (sec == 1) {
                outp[(size_t)(4 * i + 2) * CC + lrow] = v;
                outp[(size_t)(2046 - 4 * i) * CC + lrow] = v;
            } else if (sec == 2) {
                outp[(size_t)(2 * i + 1) * CC + lrow] = v;
                outp[(size_t)(2047 - 2 * i) * CC + lrow] = v;
            } else {
                outp[(size_t)(513 + 2 * i) * CC + lrow] = v;
                outp[(size_t)(1535 - 2 * i) * CC + lrow] = v;
            }
        }
    }
}

// ---------------- kernel 2: fused fold + triple GEMM -----------------------
// 256 blocks (1/CU), 512 threads. Block owns 16 output cols (b = blk>>4).
__global__ __launch_bounds__(512) void fused_kernel(
    const float* __restrict__ x,
    const bf16_t* __restrict__ Aee, const bf16_t* __restrict__ Aeo,
    const bf16_t* __restrict__ Ao, float* __restrict__ out)
{
    __shared__ bf16_t AsL[2][16384];   // 64 KB A staging (dbuf)
    __shared__ bf16_t Ylds[Y_ELEMS];   // 34 KB folded inputs
    __shared__ float red[16][32];

    const int blk = blockIdx.x;
    const int t = threadIdx.x;
    const int b = blk >> 4;
    const int c0 = (blk & 15) << 4;
    const int col = t & 15;
    const int colk = col & 7;

    // zero Yee chunks 32..39 (p=257..319 pad region; ee256 overwrites its slot)
    {
        const int zc = t >> 5;          // col 0..15
        const int zo = t & 31;          // u32 offset
        *reinterpret_cast<unsigned*>(&Ylds[YEE_OFF + zc * KEE + 256 + zo * 2]) = 0u;
    }
    __syncthreads();

    // ---- phase A: register fold (R5-proven math), swizzled LDS writes ----
    {
        const float* xcol = x + (size_t)b * NN * CC + c0 + col;
        const int pg = t >> 4;          // 0..31
#pragma unroll
        for (int j = 0; j < 8; ++j) {
            const int p = pg + 32 * j;
            const int n2 = 512 - p, n3 = 512 + p, n4 = 1024 - p;
            const int n5 = 1024 + p, n6 = 1536 - p, n7 = 1536 + p;
            const int n8 = (2048 - p) & 2047;
            const float x1 = xcol[(size_t)p  * CC];
            const float x2 = xcol[(size_t)n2 * CC];
            const float x3 = xcol[(size_t)n3 * CC];
            const float x4 = xcol[(size_t)n4 * CC];
            const float x5 = xcol[(size_t)n5 * CC];
            const float x6 = xcol[(size_t)n6 * CC];
            const float x7 = xcol[(size_t)n7 * CC];
            const float x8 = xcol[(size_t)n8 * CC];
            const float wgt = (p == 0) ? 0.5f : 1.0f;
            const float e_lo = wgt * ((x1 + x4) + (x5 + x8));
            const float e_hi = wgt * ((x2 + x3) + (x6 + x7));
            const float ol = wgt * ((x1 - x5) - (x4 - x8));
            float oh = (x2 - x6) - (x3 - x7);   // o[512-p] -> slot u=256+p
            if (p == 0) {                       // slot u=256 carries o[256]
                const float a  = xcol[(size_t)256  * CC];
                const float bb = xcol[(size_t)768  * CC];
                const float c  = xcol[(size_t)1280 * CC];
                const float d  = xcol[(size_t)1792 * CC];
                oh = (a - c) - (bb - d);
            }
            Ylds[YEE_OFF + col * KEE + swz8(p, colk)] = (bf16_t)(e_lo + e_hi);
            Ylds[YEO_OFF + col * KEO + swz8(p, colk)] = (bf16_t)(e_lo - e_hi);
            Ylds[YO_OFF  + col * KO  + swz8(p, colk)] = (bf16_t)ol;
            Ylds[YO_OFF  + col * KO  + swz8(256 + p, colk)] = (bf16_t)oh;
        }
        if ((t >> 4) == 0) {            // ee[256]
            const float ee256 = (xcol[(size_t)256 * CC] + xcol[(size_t)768 * CC]) +
                                (xcol[(size_t)1280 * CC] + xcol[(size_t)1792 * CC]);
            Ylds[YEE_OFF + col * KEE + swz8(256, colk)] = (bf16_t)ee256;
        }
    }
    __syncthreads();

    // ---- GEMV partials: out[1024] = sum_p (-1)^p ee[p] ----
    {
        const int part = t >> 4;        // chunk 0..31 (p = part*8+q, parity = q)
        const int phys = (((part & ~7) | ((part & 7) ^ colk)) << 3);
        const bf16x8 v = *(const bf16x8*)&Ylds[YEE_OFF + col * KEE + phys];
        float s = 0.f;
#pragma unroll
        for (int q = 0; q < 8; ++q) s += (q & 1) ? -(float)v[q] : (float)v[q];
        red[col][part] = s;
    }
    __syncthreads();
    if (t < 16) {
        float s = 0.f;
#pragma unroll
        for (int q = 0; q < 32; ++q) s += red[t][q];
        s += (float)Ylds[YEE_OFF + t * KEE + swz8(256, t & 7)];
        out[(size_t)b * NN * CC + (size_t)1024 * CC + c0 + t] = s;
    }

    // ---- phase B: four GEMM sections ----
    float* outp = out + (size_t)b * NN * CC + c0;
    bf16_t* AsBuf = &AsL[0][0];
    gemm_section(Aee,                 KEE, Ylds, YEE_OFF, AsBuf, outp, 0, t);
    gemm_section(Aeo,                 KEO, Ylds, YEO_OFF, AsBuf, outp, 1, t);
    gemm_section(Ao,                  KO,  Ylds, YO_OFF,  AsBuf, outp, 2, t);
    gemm_section(Ao + (size_t)256 * KO, KO, Ylds, YO_OFF, AsBuf, outp, 3, t);
}

// ---------------- fallback (no/small ws): correct but slow ----------------

__global__ void fallback_kernel(const float* __restrict__ x, float* __restrict__ out) {
    __shared__ float tbl[NN];
    const int b = blockIdx.y;
    const int kbase = blockIdx.x * 16;
    const int t = threadIdx.x;  // 256 = C
    for (int i = t; i < NN; i += 256)
        tbl[i] = cosf((float)i * ANG2);
    __syncthreads();
    float acc[16];
#pragma unroll
    for (int kk = 0; kk < 16; ++kk) acc[kk] = 0.f;
    const float* xb = x + (size_t)b * NN * CC;
    for (int n = 0; n < NN; ++n) {
        const float xv = xb[(size_t)n * CC + t];
#pragma unroll
        for (int kk = 0; kk < 16; ++kk) {
            const int m = (n * (kbase + kk)) & (NN - 1);
            acc[kk] += tbl[m] * xv;
        }
    }
#pragma unroll
    for (int kk = 0; kk < 16; ++kk)
        out[((size_t)b * NN + kbase + kk) * CC + t] = acc[kk];
}

extern "C" void kernel_launch(void* const* d_in, const int* in_sizes, int n_in,
                              void* d_out, int out_size, void* d_ws, size_t ws_size,
                              hipStream_t stream) {
    const float* x = (const float*)d_in[0];
    float* out = (float*)d_out;

    const size_t Aee_b = (size_t)256 * KEE * 2;      // 163,840
    const size_t Aeo_b = (size_t)256 * KEO * 2;      // 131,072
    const size_t Ao_b  = (size_t)512 * KO  * 2;      // 524,288
    const size_t need = Aee_b + Aeo_b + Ao_b;        // ~0.8 MB

    if (ws_size >= need) {
        char* p = (char*)d_ws;
        bf16_t* Aee = (bf16_t*)p;              p += Aee_b;
        bf16_t* Aeo = (bf16_t*)p;              p += Aeo_b;
        bf16_t* Ao  = (bf16_t*)p;
        build_A_kernel<<<NBLK_A, 256, 0, stream>>>(Aee, Aeo, Ao);
        fused_kernel<<<256, 512, 0, stream>>>(x, Aee, Aeo, Ao, out);
    } else {
        fallback_kernel<<<dim3(NN / 16, BB), CC, 0, stream>>>(x, out);
    }
}

// Round 8
// 27.317 us; speedup vs baseline: 1.4564x; 1.4564x over previous
//
#include <hip/hip_runtime.h>
#include <hip/hip_bf16.h>
#include <math.h>

typedef __bf16 bf16_t;
typedef __attribute__((ext_vector_type(8))) __bf16 bf16x8;
typedef __attribute__((ext_vector_type(4))) float f32x4;

#define NN 2048
#define CC 256
#define BB 16
#define COLS 4096          // flattened (b,c)

// Sub-transforms (out[k], k=0..2047):
//  EE: out[4i]   = sum_{p=0}^{256} ee[p] cos(2pi*p*i/512),       i=0..255 (+mirror; k=1024 via GEMV)
//  EO: out[4i+2] = sum_{m=0}^{255} eo[m] cos(2pi*m*(2i+1)/1024), i=0..255 (+mirror)
//  O : out[2j+1] = sum_{m=0}^{511} o[m]  cos(2pi*m*(2j+1)/2048), j=0..511 (+mirror)
//  O K-axis PERMUTED: u<256 -> m=u ; u==256 -> m=256 ; u>256 -> m=768-u
#define KEE 320            // 257 padded to 5*64
#define MEE 256
#define KEO 256
#define KO  512

#define ANG2 (6.283185307179586f / 2048.0f)
#define ANG1 (6.283185307179586f / 1024.0f)
#define ANG0 (6.283185307179586f / 512.0f)

__device__ __forceinline__ void gload_lds16(const void* g, void* l) {
    __builtin_amdgcn_global_load_lds(
        (const __attribute__((address_space(1))) void*)g,
        (__attribute__((address_space(3))) void*)l, 16, 0, 0);
}

union V8 { bf16_t h[8]; uint4 v; };

// ---------------- prologue: A-build + register-only fold (R6-proven) -------
#define NBLK_AEE 40
#define NBLK_AEO 32
#define NBLK_AO  128
#define NBLK_A   (NBLK_AEE + NBLK_AEO + NBLK_AO)
#define NBLK_FOLD 512
#define PREP_BLOCKS (NBLK_A + NBLK_FOLD + 64)

__global__ __launch_bounds__(256) void prep_kernel(
    const float* __restrict__ x,
    bf16_t* __restrict__ Aee, bf16_t* __restrict__ Aeo, bf16_t* __restrict__ Ao,
    bf16_t* __restrict__ Yee, bf16_t* __restrict__ Yeo, bf16_t* __restrict__ Yo)
{
    const int blk = blockIdx.x;
    const int t = threadIdx.x;

    if (blk < NBLK_AEE) {              // Aee[i][p] = cos(2pi*p*i/512), zero p>256
        const int u = blk * 256 + t;
        const int i = u / 40;
        const int p0 = (u - i * 40) * 8;
        const unsigned step = (unsigned)i & 511u;
        unsigned ph = ((unsigned)i * (unsigned)p0) & 511u;
        V8 vals;
#pragma unroll
        for (int q = 0; q < 8; ++q) {
            vals.h[q] = (p0 + q <= 256) ? (bf16_t)cosf((float)ph * ANG0) : (bf16_t)0.0f;
            ph = (ph + step) & 511u;
        }
        *reinterpret_cast<uint4*>(Aee + (size_t)i * KEE + p0) = vals.v;
        return;
    }
    if (blk < NBLK_AEE + NBLK_AEO) {   // Aeo[i][m] = cos(2pi*m*(2i+1)/1024)
        const int u = (blk - NBLK_AEE) * 256 + t;
        const int i = u >> 5;
        const int m0 = (u & 31) * 8;
        const unsigned tw = 2u * (unsigned)i + 1u;
        unsigned ph = ((unsigned)m0 * tw) & 1023u;
        V8 vals;
#pragma unroll
        for (int q = 0; q < 8; ++q) {
            vals.h[q] = (bf16_t)cosf((float)ph * ANG1);
            ph = (ph + tw) & 1023u;
        }
        *reinterpret_cast<uint4*>(Aeo + (size_t)i * KEO + m0) = vals.v;
        return;
    }
    if (blk < NBLK_A) {                // Ao[j][u] = cos(2pi*m(u)*(2j+1)/2048)
        const int u = (blk - NBLK_AEE - NBLK_AEO) * 256 + t;
        const int j = u >> 6;
        const int u0 = (u & 63) * 8;
        const unsigned tw = 2u * (unsigned)j + 1u;
        V8 vals;
#pragma unroll
        for (int q = 0; q < 8; ++q) {
            const int uu = u0 + q;
            const int m = (uu <= 256) ? uu : (768 - uu);
            const unsigned ph = ((unsigned)m * tw) & 2047u;
            vals.h[q] = (bf16_t)cosf((float)ph * ANG2);
        }
        *reinterpret_cast<uint4*>(Ao + (size_t)j * KO + u0) = vals.v;
        return;
    }

    if (blk < NBLK_A + NBLK_FOLD) {
        // ---- fold: (p-tile, col-tile), all register, all aligned ----
        const int f = blk - NBLK_A;
        const int pt = f >> 6;             // 0..7
        const int ct = f & 63;             // 0..63
        const int gc0 = ct * 64;
        const int col = t & 63;
        const int pg = t >> 6;             // wave id 0..3
        const int p_base = pt * 32 + pg * 8;
        const float* xcol = x + (size_t)(gc0 >> 8) * NN * CC + (gc0 & 255) + col;

        float eeV[8], eoV[8], olV[8], ohV[8];
#pragma unroll
        for (int q = 0; q < 8; ++q) {
            const int p = p_base + q;
            const int n2 = 512 - p, n3 = 512 + p, n4 = 1024 - p;
            const int n5 = 1024 + p, n6 = 1536 - p, n7 = 1536 + p;
            const int n8 = (2048 - p) & 2047;
            const float x1 = xcol[(size_t)p  * CC];
            const float x2 = xcol[(size_t)n2 * CC];
            const float x3 = xcol[(size_t)n3 * CC];
            const float x4 = xcol[(size_t)n4 * CC];
            const float x5 = xcol[(size_t)n5 * CC];
            const float x6 = xcol[(size_t)n6 * CC];
            const float x7 = xcol[(size_t)n7 * CC];
            const float x8 = xcol[(size_t)n8 * CC];
            const float w = (p == 0) ? 0.5f : 1.0f;
            const float e_lo = w * ((x1 + x4) + (x5 + x8));
            const float e_hi = w * ((x2 + x3) + (x6 + x7));
            olV[q] = w * ((x1 - x5) - (x4 - x8));
            ohV[q] = (x2 - x6) - (x3 - x7);       // o[512-p] -> slot u=256+p
            eeV[q] = e_lo + e_hi;
            eoV[q] = e_lo - e_hi;
        }
        if (pt == 0 && pg == 0) {
            // p==0 lane: oh slot u=256 must carry o[256]
            const float a = xcol[(size_t)256  * CC];
            const float b2 = xcol[(size_t)768  * CC];
            const float c = xcol[(size_t)1280 * CC];
            const float d = xcol[(size_t)1792 * CC];
            ohV[0] = (a - c) - (b2 - d);
        }
        V8 vee, veo, vol, voh;
#pragma unroll
        for (int q = 0; q < 8; ++q) {
            vee.h[q] = (bf16_t)eeV[q]; veo.h[q] = (bf16_t)eoV[q];
            vol.h[q] = (bf16_t)olV[q]; voh.h[q] = (bf16_t)ohV[q];
        }
        const size_t gcol = (size_t)(gc0 + col);
        *reinterpret_cast<uint4*>(Yee + gcol * KEE + p_base) = vee.v;
        *reinterpret_cast<uint4*>(Yeo + gcol * KEO + p_base) = veo.v;
        *reinterpret_cast<uint4*>(Yo  + gcol * KO  + p_base) = vol.v;
        *reinterpret_cast<uint4*>(Yo  + gcol * KO  + 256 + p_base) = voh.v;
        return;
    }

    // ---- p=256 tile: ee[256] + zero-fill Yee[257..319] ----
    {
        const int ct = blk - (NBLK_A + NBLK_FOLD);
        if (t >= 64) return;
        const int gc0 = ct * 64;
        const float* xcol = x + (size_t)(gc0 >> 8) * NN * CC + (gc0 & 255) + t;
        const float ee256 = (xcol[(size_t)256 * CC] + xcol[(size_t)768 * CC]) +
                            (xcol[(size_t)1280 * CC] + xcol[(size_t)1792 * CC]);
        bf16_t* base = Yee + (size_t)(gc0 + t) * KEE + 256;
        V8 z; z.v = make_uint4(0, 0, 0, 0);
        V8 first = z; first.h[0] = (bf16_t)ee256;
        *reinterpret_cast<uint4*>(base) = first.v;
#pragma unroll
        for (int ch = 1; ch < 8; ++ch)
            *reinterpret_cast<uint4*>(base + ch * 8) = z.v;
    }
}

// ---------------- triple GEMM + GEMV, one launch ----------------
// grid (32, 13): y 0..3 EE (BM=64), 4..7 EO (BM=64), 8..11 O (BM=128), 12 GEMV.
// BN=128 everywhere (halves A re-reads, doubles MFMA per staged byte).
// dbuf LDS + linear gload_lds dest + pre-swizzled source + swizzled ds_read.

__global__ __launch_bounds__(256) void gemm_kernel(
    const bf16_t* __restrict__ Aee, const bf16_t* __restrict__ Aeo,
    const bf16_t* __restrict__ Ao,
    const bf16_t* __restrict__ Yee, const bf16_t* __restrict__ Yeo,
    const bf16_t* __restrict__ Yo, float* __restrict__ out)
{
    __shared__ bf16_t As[2][128 * 64];   // 32 KB
    __shared__ bf16_t Bs[2][128 * 64];   // 32 KB
    __shared__ float red[128][2];

    const int col0 = blockIdx.x * 128;
    const int yb = blockIdx.y;
    const int t = threadIdx.x;

    if (yb == 12) {                    // ---- GEMV: out[1024][c] = sum (-1)^p ee[p]
        const int col = t & 127;
        const int part = t >> 7;       // 0..1
        const bf16_t* yc = Yee + (size_t)(col0 + col) * KEE + part * 160;
        float s = 0.f;
#pragma unroll
        for (int jc = 0; jc < 20; ++jc) {
            const bf16x8 v = *reinterpret_cast<const bf16x8*>(yc + jc * 8);
#pragma unroll
            for (int q = 0; q < 8; ++q)
                s += (q & 1) ? -(float)v[q] : (float)v[q];
        }
        red[col][part] = s;
        __syncthreads();
        if (t < 128) {
            const float tot = red[t][0] + red[t][1];
            const int gc = col0 + t;
            out[(size_t)(gc >> 8) * NN * CC + (size_t)1024 * CC + (gc & 255)] = tot;
        }
        return;
    }

    const bf16_t *Ab, *Bb;
    int row0, kdim, half;
    if (yb < 4)      { half = 0; row0 = yb * 64;        kdim = KEE; Ab = Aee + (size_t)row0 * KEE; Bb = Yee + (size_t)col0 * KEE; }
    else if (yb < 8) { half = 1; row0 = (yb - 4) * 64;  kdim = KEO; Ab = Aeo + (size_t)row0 * KEO; Bb = Yeo + (size_t)col0 * KEO; }
    else             { half = 2; row0 = (yb - 8) * 128; kdim = KO;  Ab = Ao  + (size_t)row0 * KO;  Bb = Yo  + (size_t)col0 * KO; }
    const int ksteps = kdim >> 6;

    const int lane = t & 63;
    const int wid = t >> 6;
    const int wr = wid >> 1, wc = wid & 1;
    const int srow = t >> 3;             // 0..31
    const int sc_chunk = t & 7;          // 16B-chunk index within the 64-elem row
    const int s_swz = (sc_chunk ^ (srow & 7)) * 8;   // swizzled source elem offset
    const int lds_lin = srow * 64 + sc_chunk * 8;    // linear dest elem offset
    const int lrow = lane & 15;
    const int rx8 = lrow & 7;            // read-side swizzle key
    const int rgrp = lane >> 4;
    const int cl = lane & 15;
    const int hi8 = (lane >> 4) * 8;     // koff base within kk-group

    if (half == 2) {                   // ---- O: BM=128, BN=128, ksteps=8 ----
        f32x4 acc[4][4] = {};
        int cur = 0;
#pragma unroll
        for (int it = 0; it < 4; ++it) {
            gload_lds16(Ab + (size_t)(srow + it * 32) * KO + s_swz,
                        &As[0][lds_lin + it * 2048]);
            gload_lds16(Bb + (size_t)(srow + it * 32) * KO + s_swz,
                        &Bs[0][lds_lin + it * 2048]);
        }
        __syncthreads();
        for (int kt = 0; kt < 8; ++kt) {
            if (kt + 1 < 8) {
                const int k0 = (kt + 1) * 64;
#pragma unroll
                for (int it = 0; it < 4; ++it) {
                    gload_lds16(Ab + (size_t)(srow + it * 32) * KO + k0 + s_swz,
                                &As[cur ^ 1][lds_lin + it * 2048]);
                    gload_lds16(Bb + (size_t)(srow + it * 32) * KO + k0 + s_swz,
                                &Bs[cur ^ 1][lds_lin + it * 2048]);
                }
            }
            const bf16_t* as = &As[cur][0];
            const bf16_t* bs = &Bs[cur][0];
#pragma unroll
            for (int kk = 0; kk < 64; kk += 32) {
                const int g = (kk + hi8) >> 3;           // global chunk 0..7
                const int rc = ((g ^ rx8) * 8);          // swizzled read offset
                bf16x8 af[4], bfr[4];
#pragma unroll
                for (int m = 0; m < 4; ++m)
                    af[m] = *(const bf16x8*)&as[(wr * 64 + m * 16 + lrow) * 64 + rc];
#pragma unroll
                for (int n = 0; n < 4; ++n)
                    bfr[n] = *(const bf16x8*)&bs[(wc * 64 + n * 16 + lrow) * 64 + rc];
#pragma unroll
                for (int m = 0; m < 4; ++m)
#pragma unroll
                    for (int n = 0; n < 4; ++n)
                        acc[m][n] = __builtin_amdgcn_mfma_f32_16x16x32_bf16(
                            af[m], bfr[n], acc[m][n], 0, 0, 0);
            }
            __syncthreads();
            cur ^= 1;
        }
#pragma unroll
        for (int m = 0; m < 4; ++m)
#pragma unroll
            for (int n = 0; n < 4; ++n) {
                const int col = col0 + wc * 64 + n * 16 + cl;
                float* obc = out + (size_t)(col >> 8) * NN * CC + (col & 255);
#pragma unroll
                for (int r = 0; r < 4; ++r) {
                    const int j = row0 + wr * 64 + m * 16 + rgrp * 4 + r;
                    const float v = acc[m][n][r];
                    obc[(size_t)(2 * j + 1) * CC] = v;
                    obc[(size_t)(2047 - 2 * j) * CC] = v;
                }
            }
    } else {                           // ---- EE / EO: BM=64, BN=128 ----
        f32x4 acc[2][4] = {};
        int cur = 0;
#pragma unroll
        for (int it = 0; it < 2; ++it)
            gload_lds16(Ab + (size_t)(srow + it * 32) * kdim + s_swz,
                        &As[0][lds_lin + it * 2048]);
#pragma unroll
        for (int it = 0; it < 4; ++it)
            gload_lds16(Bb + (size_t)(srow + it * 32) * kdim + s_swz,
                        &Bs[0][lds_lin + it * 2048]);
        __syncthreads();
        for (int kt = 0; kt < ksteps; ++kt) {
            if (kt + 1 < ksteps) {
                const int k0 = (kt + 1) * 64;
#pragma unroll
                for (int it = 0; it < 2; ++it)
                    gload_lds16(Ab + (size_t)(srow + it * 32) * kdim + k0 + s_swz,
                                &As[cur ^ 1][lds_lin + it * 2048]);
#pragma unroll
                for (int it = 0; it < 4; ++it)
                    gload_lds16(Bb + (size_t)(srow + it * 32) * kdim + k0 + s_swz,
                                &Bs[cur ^ 1][lds_lin + it * 2048]);
            }
            const bf16_t* as = &As[cur][0];
            const bf16_t* bs = &Bs[cur][0];
#pragma unroll
            for (int kk = 0; kk < 64; kk += 32) {
                const int g = (kk + hi8) >> 3;
                const int rc = ((g ^ rx8) * 8);
                bf16x8 af[2], bfr[4];
#pragma unroll
                for (int m = 0; m < 2; ++m)
                    af[m] = *(const bf16x8*)&as[(wr * 32 + m * 16 + lrow) * 64 + rc];
#pragma unroll
                for (int n = 0; n < 4; ++n)
                    bfr[n] = *(const bf16x8*)&bs[(wc * 64 + n * 16 + lrow) * 64 + rc];
#pragma unroll
                for (int m = 0; m < 2; ++m)
#pragma unroll
                    for (int n = 0; n < 4; ++n)
                        acc[m][n] = __builtin_amdgcn_mfma_f32_16x16x32_bf16(
                            af[m], bfr[n], acc[m][n], 0, 0, 0);
            }
            __syncthreads();
            cur ^= 1;
        }
#pragma unroll
        for (int m = 0; m < 2; ++m)
#pragma unroll
            for (int n = 0; n < 4; ++n) {
                const int col = col0 + wc * 64 + n * 16 + cl;
                float* obc = out + (size_t)(col >> 8) * NN * CC + (col & 255);
#pragma unroll
                for (int r = 0; r < 4; ++r) {
                    const int i = row0 + wr * 32 + m * 16 + rgrp * 4 + r;  // 0..255
                    const float v = acc[m][n][r];
                    if (half == 0) {
                        obc[(size_t)(4 * i) * CC] = v;
                        if (i >= 1) obc[(size_t)(2048 - 4 * i) * CC] = v;
                    } else {
                        obc[(size_t)(4 * i + 2) * CC] = v;
                        obc[(size_t)(2046 - 4 * i) * CC] = v;
                    }
                }
            }
    }
}

// ---------------- fallback (no/small ws): correct but slow ----------------

__global__ void fallback_kernel(const float* __restrict__ x, float* __restrict__ out) {
    __shared__ float tbl[NN];
    const int b = blockIdx.y;
    const int kbase = blockIdx.x * 16;
    const int t = threadIdx.x;  // 256 = C
    for (int i = t; i < NN; i += 256)
        tbl[i] = cosf((float)i * ANG2);
    __syncthreads();
    float acc[16];
#pragma unroll
    for (int kk = 0; kk < 16; ++kk) acc[kk] = 0.f;
    const float* xb = x + (size_t)b * NN * CC;
    for (int n = 0; n < NN; ++n) {
        const float xv = xb[(size_t)n * CC + t];
#pragma unroll
        for (int kk = 0; kk < 16; ++kk) {
            const int m = (n * (kbase + kk)) & (NN - 1);
            acc[kk] += tbl[m] * xv;
        }
    }
#pragma unroll
    for (int kk = 0; kk < 16; ++kk)
        out[((size_t)b * NN + kbase + kk) * CC + t] = acc[kk];
}

extern "C" void kernel_launch(void* const* d_in, const int* in_sizes, int n_in,
                              void* d_out, int out_size, void* d_ws, size_t ws_size,
                              hipStream_t stream) {
    const float* x = (const float*)d_in[0];
    float* out = (float*)d_out;

    const size_t Aee_b = (size_t)MEE * KEE * 2;      // 163,840
    const size_t Aeo_b = (size_t)256 * KEO * 2;      // 131,072
    const size_t Ao_b  = (size_t)512 * KO  * 2;      // 524,288
    const size_t Yee_b = (size_t)COLS * KEE * 2;     // 2,621,440
    const size_t Yeo_b = (size_t)COLS * KEO * 2;     // 2,097,152
    const size_t Yo_b  = (size_t)COLS * KO  * 2;     // 4,194,304
    const size_t need = Aee_b + Aeo_b + Ao_b + Yee_b + Yeo_b + Yo_b;

    if (ws_size >= need) {
        char* p = (char*)d_ws;
        bf16_t* Aee = (bf16_t*)p;              p += Aee_b;
        bf16_t* Aeo = (bf16_t*)p;              p += Aeo_b;
        bf16_t* Ao  = (bf16_t*)p;              p += Ao_b;
        bf16_t* Yee = (bf16_t*)p;              p += Yee_b;
        bf16_t* Yeo = (bf16_t*)p;              p += Yeo_b;
        bf16_t* Yo  = (bf16_t*)p;
        prep_kernel<<<PREP_BLOCKS, 256, 0, stream>>>(x, Aee, Aeo, Ao, Yee, Yeo, Yo);
        gemm_kernel<<<dim3(COLS / 128, 13), 256, 0, stream>>>(Aee, Aeo, Ao, Yee, Yeo, Yo, out);
    } else {
        fallback_kernel<<<dim3(NN / 16, BB), CC, 0, stream>>>(x, out);
    }
}